// Round 1
// baseline (306.262 us; speedup 1.0000x reference)
//
#include <hip/hip_runtime.h>

// Problem: y[e] = W2 . relu(W1 . concat(z[src[e]], z[dst[e]]) + b1) + b2
// N=50000, D=128, H=512, E=500000. Compute-bound: 131 GFLOP in GEMM1.
// Strategy: bf16 MFMA (16x16x32), fused gather + GEMM1 + relu + GEMM2.

typedef __bf16 bf16x8 __attribute__((ext_vector_type(8)));
typedef float f32x4 __attribute__((ext_vector_type(4)));

#define STRA 264   // 256 + 8 pad (ushort units) -> 2-way LDS conflicts only (free)
#define STRB 40    // 32 + 8 pad

__device__ __forceinline__ unsigned short f2b(float f) {
    unsigned int u = __float_as_uint(f);
    u = (u + 0x7fffu + ((u >> 16) & 1u)) >> 16;   // RNE
    return (unsigned short)u;
}

__global__ void prep_kernel(const float* __restrict__ z, const float* __restrict__ W1,
                            unsigned short* __restrict__ zb, unsigned short* __restrict__ w1b,
                            int nz4, int nw4) {
    int stride = gridDim.x * blockDim.x;
    for (int idx = blockIdx.x * blockDim.x + threadIdx.x; idx < nz4 + nw4; idx += stride) {
        const float4* src;
        unsigned short* dst;
        int k;
        if (idx < nz4) { src = (const float4*)z;  dst = zb;  k = idx; }
        else           { src = (const float4*)W1; dst = w1b; k = idx - nz4; }
        float4 v = src[k];
        ushort4 o;
        o.x = f2b(v.x); o.y = f2b(v.y); o.z = f2b(v.z); o.w = f2b(v.w);
        ((ushort4*)dst)[k] = o;
    }
}

__global__ __launch_bounds__(256, 2)
void edge_mlp_kernel(const int* __restrict__ ei, const unsigned short* __restrict__ zb,
                     const unsigned short* __restrict__ w1b,
                     const float* __restrict__ b1, const float* __restrict__ W2,
                     const float* __restrict__ b2p, float* __restrict__ out, int E) {
    __shared__ unsigned short ldsA[128 * STRA];  // 67584 B : 128 edges x 256 k (bf16)
    __shared__ unsigned short ldsB[128 * STRB];  // 10240 B : 128 h x 32 k strip

    const int tid  = threadIdx.x;
    const int lane = tid & 63;
    const int w    = tid >> 6;
    const int wrow = w & 1;        // M-half of 128x128 chunk (64 edges)
    const int wcol = w >> 1;       // N-half (64 h)
    const int l15  = lane & 15;
    const int l4   = lane >> 4;
    const int ebase = blockIdx.x * 128;

    // ---- gather A: 128 edges x (z[src] ++ z[dst]) as bf16 rows ----
    {
        const int g = tid >> 4;     // 16 groups of 16 lanes
        const int l = tid & 15;
        for (int it = 0; it < 16; ++it) {
            int hr = it * 16 + g;          // half-row 0..255
            int m = hr >> 1, side = hr & 1;
            int e = ebase + m;
            int row = 0;
            if (e < E) row = side ? ei[E + e] : ei[e];
            // one z row = 128 bf16 = 256 B = 16 lanes x 16 B (coalesced)
            uint4 v = *((const uint4*)(zb + (row << 7)) + l);
            *(uint4*)&ldsA[m * STRA + side * 128 + l * 8] = v;
        }
    }

    float y[4][4];
    #pragma unroll
    for (int i = 0; i < 4; i++)
        #pragma unroll
        for (int r = 0; r < 4; r++) y[i][r] = 0.f;

    const unsigned aoffbase = (wrow * 64 + l15) * STRA + l4 * 8;
    const unsigned boffbase = (wcol * 64 + l15) * STRB + l4 * 8;
    const int bn  = tid >> 1;          // 0..127 : h row within strip
    const int bko = (tid & 1) * 16;    // 0 or 16 : k offset within strip

    for (int nc = 0; nc < 4; ++nc) {
        f32x4 acc[4][4];
        #pragma unroll
        for (int i = 0; i < 4; i++)
            #pragma unroll
            for (int j = 0; j < 4; j++) acc[i][j] = (f32x4){0.f, 0.f, 0.f, 0.f};

        // prefetch strip kc=0 (32 B/thread)
        const unsigned short* wp = w1b + (nc * 128 + bn) * 256 + bko;
        uint4 p0 = *(const uint4*)(wp);
        uint4 p1 = *(const uint4*)(wp + 8);

        for (int kc = 0; kc < 8; ++kc) {
            __syncthreads();                       // prior strip reads done
            *(uint4*)&ldsB[bn * STRB + bko]     = p0;
            *(uint4*)&ldsB[bn * STRB + bko + 8] = p1;
            __syncthreads();                       // strip visible
            if (kc < 7) {                          // overlap next strip load with MFMAs
                const unsigned short* wp2 = wp + (kc + 1) * 32;
                p0 = *(const uint4*)(wp2);
                p1 = *(const uint4*)(wp2 + 8);
            }
            bf16x8 a[4], b[4];
            #pragma unroll
            for (int i = 0; i < 4; i++)
                a[i] = *(const bf16x8*)&ldsA[aoffbase + i * 16 * STRA + kc * 32];
            #pragma unroll
            for (int j = 0; j < 4; j++)
                b[j] = *(const bf16x8*)&ldsB[boffbase + j * 16 * STRB];
            #pragma unroll
            for (int i = 0; i < 4; i++)
                #pragma unroll
                for (int j = 0; j < 4; j++)
                    acc[i][j] = __builtin_amdgcn_mfma_f32_16x16x32_bf16(a[i], b[j], acc[i][j], 0, 0, 0);
        }

        // fused epilogue: h = relu(acc + b1); y += h * W2[h]
        #pragma unroll
        for (int j = 0; j < 4; j++) {
            int h = nc * 128 + wcol * 64 + j * 16 + l15;
            float w2v = W2[h];
            float b1v = b1[h];
            #pragma unroll
            for (int i = 0; i < 4; i++)
                #pragma unroll
                for (int r = 0; r < 4; r++) {
                    float hv = acc[i][j][r] + b1v;
                    y[i][r] = fmaf(fmaxf(hv, 0.f), w2v, y[i][r]);
                }
        }
    }

    // reduce over the 16 N-lanes (C layout: col = lane&15)
    #pragma unroll
    for (int i = 0; i < 4; i++)
        #pragma unroll
        for (int r = 0; r < 4; r++) {
            float v = y[i][r];
            v += __shfl_xor(v, 1);
            v += __shfl_xor(v, 2);
            v += __shfl_xor(v, 4);
            v += __shfl_xor(v, 8);
            y[i][r] = v;
        }

    __syncthreads();                 // done reading ldsB; reuse as ldsY
    float* ldsY = (float*)ldsB;
    if (l15 == 0) {
        #pragma unroll
        for (int i = 0; i < 4; i++)
            #pragma unroll
            for (int r = 0; r < 4; r++) {
                int m = wrow * 64 + i * 16 + l4 * 4 + r;   // C layout: row=(lane>>4)*4+reg
                ldsY[wcol * 128 + m] = y[i][r];
            }
    }
    __syncthreads();
    if (tid < 128) {
        int e = ebase + tid;
        if (e < E) out[e] = ldsY[tid] + ldsY[128 + tid] + b2p[0];
    }
}

extern "C" void kernel_launch(void* const* d_in, const int* in_sizes, int n_in,
                              void* d_out, int out_size, void* d_ws, size_t ws_size,
                              hipStream_t stream) {
    const float* z  = (const float*)d_in[0];
    const int*   ei = (const int*)d_in[1];
    const float* W1 = (const float*)d_in[2];
    const float* b1 = (const float*)d_in[3];
    const float* W2 = (const float*)d_in[4];
    const float* b2 = (const float*)d_in[5];
    float* out = (float*)d_out;

    const int E  = in_sizes[1] / 2;   // 500000
    const int NZ = in_sizes[0];       // 6400000 = N*D
    const int NW = in_sizes[2];       // 131072  = H*2D

    unsigned short* zb  = (unsigned short*)d_ws;       // 12.8 MB
    unsigned short* w1b = zb + NZ;                     // 256 KB

    prep_kernel<<<2048, 256, 0, stream>>>(z, W1, zb, w1b, NZ / 4, NW / 4);

    const int blocks = (E + 127) / 128;                // 3907
    edge_mlp_kernel<<<blocks, 256, 0, stream>>>(ei, zb, w1b, b1, W2, b2, out, E);
}